// Round 5
// baseline (137.108 us; speedup 1.0000x reference)
//
#include <hip/hip_runtime.h>
#include <hip/hip_bf16.h>

#define SS 2048
#define DD 128
#define BB 16
#define LDST 136  // xs staging pad (ushorts)
#define SCT 268   // sc stride for qk epilogue

typedef short bf16x8 __attribute__((ext_vector_type(8)));
typedef float f32x4 __attribute__((ext_vector_type(4)));
typedef unsigned short ushort_t;

__device__ __forceinline__ unsigned short f2bf(float f) {
  union { float f; unsigned u; } v; v.f = f;
  unsigned r = v.u + 0x7fffu + ((v.u >> 16) & 1u);  // RNE
  return (unsigned short)(r >> 16);
}
__device__ __forceinline__ float fexp2(float x) { return __builtin_amdgcn_exp2f(x); }

// Fragment-major layout: chunk ((G*4 + ks)*64 + lane), 16 B each.
// G = global 16-row group (b*128 + g); lane = quad*16 + lq holds
// rows[G*16+lq], cols[ks*32+quad*8 .. +8]. Every A/B frag load is one
// coalesced global_load_dwordx4 (1 KB/wave).

// ---------------------------------------------------------------------------
// wprep: wt_g = [Wq^T * log2e/sqrt(U) ; Wk^T] bf16 [256][128]. grid 128.
// ---------------------------------------------------------------------------
__global__ __launch_bounds__(256) void wprep(
    const float* __restrict__ Wq, const float* __restrict__ Wk,
    ushort_t* __restrict__ wt_g) {
  int idx = blockIdx.x * 256 + threadIdx.x;  // 0..32767
  int r = idx & 16383, uu = r >> 7, d = r & 127;
  if (idx < 16384)
    wt_g[uu * 128 + d] = f2bf(Wq[d * 128 + uu] * 0.1275174346f);  // log2e/sqrt(128)
  else
    wt_g[(uu + 128) * 128 + d] = f2bf(Wk[d * 128 + uu]);
}

// ---------------------------------------------------------------------------
// qk_gemm: [q|k] = bf16(x) @ wt_g^T, frag-major output. grid 512, block 256.
// ---------------------------------------------------------------------------
__global__ __launch_bounds__(256, 2) void qk_gemm(
    const float* __restrict__ x, const ushort_t* __restrict__ wt_g,
    uint4* __restrict__ qF, uint4* __restrict__ kF) {
  __shared__ ushort_t xs[64 * LDST];
  __shared__ ushort_t sc[64 * SCT];
  const int tid = threadIdx.x, wave = tid >> 6, lane = tid & 63;
  const int lq = lane & 15, quad = lane >> 4;
  const int m0 = blockIdx.x * 64;

#pragma unroll
  for (int i = 0; i < 8; ++i) {  // stage x: 64x128 fp32 -> bf16
    int idx = i * 256 + tid;
    int row = idx >> 5, c4 = (idx & 31) * 4;
    const float4 v = *(const float4*)(x + (size_t)(m0 + row) * DD + c4);
    ushort4 h;
    h.x = f2bf(v.x); h.y = f2bf(v.y); h.z = f2bf(v.z); h.w = f2bf(v.w);
    *(ushort4*)(&xs[row * LDST + c4]) = h;
  }
  bf16x8 wf[4][4];  // wave's 64 output cols, K=128
#pragma unroll
  for (int nt = 0; nt < 4; ++nt)
#pragma unroll
    for (int ks = 0; ks < 4; ++ks)
      wf[nt][ks] = *(const bf16x8*)(wt_g + (wave * 64 + nt * 16 + lq) * 128 + ks * 32 + quad * 8);
  __syncthreads();

  f32x4 acc[4][4];
#pragma unroll
  for (int mt = 0; mt < 4; ++mt)
#pragma unroll
    for (int nt = 0; nt < 4; ++nt) acc[mt][nt] = (f32x4){0.f, 0.f, 0.f, 0.f};
#pragma unroll
  for (int mt = 0; mt < 4; ++mt) {
    bf16x8 af[4];
#pragma unroll
    for (int ks = 0; ks < 4; ++ks)
      af[ks] = *(const bf16x8*)(&xs[(mt * 16 + lq) * LDST + ks * 32 + quad * 8]);
#pragma unroll
    for (int nt = 0; nt < 4; ++nt)
#pragma unroll
      for (int ks = 0; ks < 4; ++ks)
        acc[mt][nt] = __builtin_amdgcn_mfma_f32_16x16x32_bf16(af[ks], wf[nt][ks], acc[mt][nt], 0, 0, 0);
  }
#pragma unroll
  for (int mt = 0; mt < 4; ++mt)
#pragma unroll
    for (int nt = 0; nt < 4; ++nt)
#pragma unroll
      for (int r = 0; r < 4; ++r)
        sc[(mt * 16 + quad * 4 + r) * SCT + wave * 64 + nt * 16 + lq] = f2bf(acc[mt][nt][r]);
  __syncthreads();
#pragma unroll
  for (int i = 0; i < 8; ++i) {  // re-read frag-order, store coalesced chunks
    int c = i * 256 + tid;
    int lane_c = c & 63, ks_c = (c >> 6) & 3, g_c = (c >> 8) & 3, isk = c >> 10;
    int li = lane_c & 15, qd = lane_c >> 4;
    int col = isk * 128 + ks_c * 32 + qd * 8;
    uint4 v = *(const uint4*)(&sc[(g_c * 16 + li) * SCT + col]);
    size_t G = (size_t)blockIdx.x * 4 + g_c;
    uint4* dst = isk ? kF : qF;
    dst[(G * 4 + ks_c) * 64 + lane_c] = v;
  }
}

// ---------------------------------------------------------------------------
// pass1: l[b,i] += sum over this block's 1024-j half of exp2 scores.
// grid 1024 = b(16) x ib(32) x jc(2); block 256 (4 waves, 4 blocks/CU);
// wave w handles 1 j-group per step, 16 steps. VGPR budget <= 128.
// ---------------------------------------------------------------------------
__global__ __launch_bounds__(256, 4) void pass1(
    const uint4* __restrict__ qF, const uint4* __restrict__ kF,
    float* __restrict__ l) {
  const int blk = blockIdx.x;
  const int jc = blk & 1, ib = (blk >> 1) & 31, b = blk >> 6;
  const int i0 = ib * 64;
  const int tid = threadIdx.x, wave = tid >> 6, lane = tid & 63;
  const int quad = lane >> 4;

  const bf16x8* qc = (const bf16x8*)qF;
  const bf16x8* kc = (const bf16x8*)kF;

  bf16x8 af[4][4];
#pragma unroll
  for (int mt = 0; mt < 4; ++mt)
#pragma unroll
    for (int ks = 0; ks < 4; ++ks)
      af[mt][ks] = qc[((size_t)(b * 128 + ib * 4 + mt) * 4 + ks) * 64 + lane];

  float rowsum[4][4];
#pragma unroll
  for (int mt = 0; mt < 4; ++mt)
#pragma unroll
    for (int r = 0; r < 4; ++r) rowsum[mt][r] = 0.f;

  for (int s = 0; s < 16; ++s) {
    const int gg = b * 128 + jc * 64 + s * 4 + wave;
    bf16x8 bf[4];
#pragma unroll
    for (int ks = 0; ks < 4; ++ks)
      bf[ks] = kc[((size_t)gg * 4 + ks) * 64 + lane];
    f32x4 acc[4];
#pragma unroll
    for (int mt = 0; mt < 4; ++mt) acc[mt] = (f32x4){0.f, 0.f, 0.f, 0.f};
#pragma unroll
    for (int ks = 0; ks < 4; ++ks)
#pragma unroll
      for (int mt = 0; mt < 4; ++mt)
        acc[mt] = __builtin_amdgcn_mfma_f32_16x16x32_bf16(af[mt][ks], bf[ks], acc[mt], 0, 0, 0);
#pragma unroll
    for (int mt = 0; mt < 4; ++mt)
#pragma unroll
      for (int r = 0; r < 4; ++r) rowsum[mt][r] += fexp2(acc[mt][r]);
  }
  // reduce over the 16 col-lanes (lq bits), then atomic into l
#pragma unroll
  for (int d2 = 1; d2 <= 8; d2 <<= 1)
#pragma unroll
    for (int mt = 0; mt < 4; ++mt)
#pragma unroll
      for (int r = 0; r < 4; ++r)
        rowsum[mt][r] += __shfl_xor(rowsum[mt][r], d2, 64);
  if ((lane & 15) == 0) {
#pragma unroll
    for (int mt = 0; mt < 4; ++mt)
#pragma unroll
      for (int r = 0; r < 4; ++r)
        atomicAdd(&l[b * SS + i0 + mt * 16 + quad * 4 + r], rowsum[mt][r]);
  }
}

// ---------------------------------------------------------------------------
// cvec: c[b,i] = sigmoid(theta_i - mu_i * t[b,i]) / l[b,i].  grid 128.
// ---------------------------------------------------------------------------
__global__ __launch_bounds__(256) void cvec(
    const float* __restrict__ t, const float* __restrict__ theta,
    const float* __restrict__ mu, const float* __restrict__ l,
    float* __restrict__ c) {
  int idx = blockIdx.x * 256 + threadIdx.x;  // 32768
  int i = idx & 2047;
  float z = theta[i] - mu[i] * t[idx];
  float tf = 1.f / (1.f + fexp2(-z * 1.44269504f));
  c[idx] = tf / l[idx];
}

// ---------------------------------------------------------------------------
// pass2: w[b,j] += sum_i c_i * exp2(s2_ij).  Same grid/shape as pass1.
// ---------------------------------------------------------------------------
__global__ __launch_bounds__(256, 4) void pass2(
    const uint4* __restrict__ qF, const uint4* __restrict__ kF,
    const float* __restrict__ c, float* __restrict__ w) {
  const int blk = blockIdx.x;
  const int jc = blk & 1, ib = (blk >> 1) & 31, b = blk >> 6;
  const int i0 = ib * 64;
  const int tid = threadIdx.x, wave = tid >> 6, lane = tid & 63;
  const int quad = lane >> 4;

  const bf16x8* qc = (const bf16x8*)qF;
  const bf16x8* kc = (const bf16x8*)kF;

  bf16x8 af[4][4];
#pragma unroll
  for (int mt = 0; mt < 4; ++mt)
#pragma unroll
    for (int ks = 0; ks < 4; ++ks)
      af[mt][ks] = qc[((size_t)(b * 128 + ib * 4 + mt) * 4 + ks) * 64 + lane];

  float creg[4][4];
#pragma unroll
  for (int mt = 0; mt < 4; ++mt)
#pragma unroll
    for (int r = 0; r < 4; ++r)
      creg[mt][r] = c[b * SS + i0 + mt * 16 + quad * 4 + r];

  for (int s = 0; s < 16; ++s) {
    const int ggl = jc * 64 + s * 4 + wave;
    const int gg = b * 128 + ggl;
    bf16x8 bf[4];
#pragma unroll
    for (int ks = 0; ks < 4; ++ks)
      bf[ks] = kc[((size_t)gg * 4 + ks) * 64 + lane];
    f32x4 acc[4];
#pragma unroll
    for (int mt = 0; mt < 4; ++mt) acc[mt] = (f32x4){0.f, 0.f, 0.f, 0.f};
#pragma unroll
    for (int ks = 0; ks < 4; ++ks)
#pragma unroll
      for (int mt = 0; mt < 4; ++mt)
        acc[mt] = __builtin_amdgcn_mfma_f32_16x16x32_bf16(af[mt][ks], bf[ks], acc[mt], 0, 0, 0);
    float cs = 0.f;
#pragma unroll
    for (int mt = 0; mt < 4; ++mt)
#pragma unroll
      for (int r = 0; r < 4; ++r) cs = fmaf(creg[mt][r], fexp2(acc[mt][r]), cs);
    cs += __shfl_xor(cs, 16, 64);
    cs += __shfl_xor(cs, 32, 64);
    if (lane < 16)
      atomicAdd(&w[b * SS + ggl * 16 + lane], cs);
  }
}

// ---------------------------------------------------------------------------
// finalize: v[b,d] = sum_j w[b,j] * x[b,j,d].  grid 512 (64 j per block).
// ---------------------------------------------------------------------------
__global__ __launch_bounds__(256) void finalize(
    const float* __restrict__ x, const float* __restrict__ w,
    float* __restrict__ out) {
  const int b = blockIdx.x >> 5;
  const int j0 = (blockIdx.x & 31) * 64;
  const int tid = threadIdx.x;
  const int d = tid & 127, jo = tid >> 7;
  float acc = 0.f;
  for (int jj = 0; jj < 32; ++jj) {
    int j = j0 + jj * 2 + jo;
    acc = fmaf(w[b * SS + j], x[((size_t)b * SS + j) * DD + d], acc);
  }
  __shared__ float red[256];
  red[tid] = acc;
  __syncthreads();
  if (tid < 128) atomicAdd(&out[b * DD + tid], red[tid] + red[tid + 128]);
}

extern "C" void kernel_launch(void* const* d_in, const int* in_sizes, int n_in,
                              void* d_out, int out_size, void* d_ws, size_t ws_size,
                              hipStream_t stream) {
  const float* x = (const float*)d_in[0];
  const float* t = (const float*)d_in[1];
  const float* Wq = (const float*)d_in[2];
  const float* Wk = (const float*)d_in[3];
  const float* theta = (const float*)d_in[4];
  const float* mu = (const float*)d_in[5];
  float* out = (float*)d_out;

  uint4* qF = (uint4*)d_ws;                                  // 8.4 MB
  uint4* kF = qF + (size_t)2048 * 4 * 64;                    // 8.4 MB
  ushort_t* wt_g = (ushort_t*)(kF + (size_t)2048 * 4 * 64);  // 64 KB
  float* l = (float*)(wt_g + 256 * 128);                     // 128 KB
  float* c = l + (size_t)BB * SS;                            // 128 KB
  float* w = c + (size_t)BB * SS;                            // 128 KB

  hipMemsetAsync(l, 0, (size_t)BB * SS * sizeof(float), stream);
  hipMemsetAsync(w, 0, (size_t)BB * SS * sizeof(float), stream);
  hipMemsetAsync(d_out, 0, (size_t)BB * DD * sizeof(float), stream);

  wprep<<<dim3(128), dim3(256), 0, stream>>>(Wq, Wk, wt_g);
  qk_gemm<<<dim3(512), dim3(256), 0, stream>>>(x, wt_g, qF, kF);
  pass1<<<dim3(1024), dim3(256), 0, stream>>>(qF, kF, l);
  cvec<<<dim3(128), dim3(256), 0, stream>>>(t, theta, mu, l, c);
  pass2<<<dim3(1024), dim3(256), 0, stream>>>(qF, kF, c, w);
  finalize<<<dim3(512), dim3(256), 0, stream>>>(x, w, out);
}